// Round 1
// baseline (608.931 us; speedup 1.0000x reference)
//
#include <hip/hip_runtime.h>
#include <math.h>

#define Bq 8
#define Lq 2048
#define Dq 1024
#define Mq (Bq*Lq)   // 16384 tokens
#define Sq 2048      // S_max
#define SP1 2049     // S_max + 1 (null group row 0)

// ---------------- init logits to b2 ----------------
__global__ void init_logits(float* __restrict__ logits, const float* __restrict__ b2) {
  int i = blockIdx.x * 256 + threadIdx.x;
  if (i < Mq) logits[i] = b2[0];
}

// ---------------- fused GEMM(relu) + GEMV -> logits ----------------
// h = relu(x @ W1 + b1); logits += h @ W2   (logits pre-initialized to b2)
#define BM 128
#define BN 128
#define BK 16
__global__ __launch_bounds__(256) void gemm_relu_gemv(
    const float* __restrict__ X, const float* __restrict__ W1,
    const float* __restrict__ b1, const float* __restrict__ W2,
    float* __restrict__ logits)
{
  __shared__ float As[BK][BM + 4];   // A stored transposed [k][m], padded
  __shared__ float Bs[BK][BN];
  __shared__ float red[BM];
  const int tid = threadIdx.x;
  const int tx = tid & 15, ty = tid >> 4;
  const int m0 = blockIdx.x * BM;
  const int n0 = blockIdx.y * BN;

  float acc[8][8];
  #pragma unroll
  for (int i = 0; i < 8; ++i)
    #pragma unroll
    for (int j = 0; j < 8; ++j) acc[i][j] = 0.f;

  for (int k0 = 0; k0 < Dq; k0 += BK) {
    #pragma unroll
    for (int s = 0; s < 2; ++s) {
      int slot = tid + s * 256;
      // A tile: 128 rows x 16 cols -> 512 float4 slots
      int r = slot >> 2, cg = slot & 3;
      float4 va = *(const float4*)(X + (size_t)(m0 + r) * Dq + k0 + cg * 4);
      As[cg*4+0][r] = va.x; As[cg*4+1][r] = va.y;
      As[cg*4+2][r] = va.z; As[cg*4+3][r] = va.w;
      // B tile: 16 rows x 128 cols -> 512 float4 slots
      int rb = slot >> 5, cgb = slot & 31;
      *(float4*)(&Bs[rb][cgb*4]) =
          *(const float4*)(W1 + (size_t)(k0 + rb) * Dq + n0 + cgb * 4);
    }
    __syncthreads();
    #pragma unroll
    for (int kk = 0; kk < BK; ++kk) {
      float a[8], bv[8];
      *(float4*)(a)     = *(const float4*)(&As[kk][ty*4]);
      *(float4*)(a + 4) = *(const float4*)(&As[kk][64 + ty*4]);
      *(float4*)(bv)    = *(const float4*)(&Bs[kk][tx*4]);
      *(float4*)(bv + 4)= *(const float4*)(&Bs[kk][64 + tx*4]);
      #pragma unroll
      for (int i = 0; i < 8; ++i)
        #pragma unroll
        for (int j = 0; j < 8; ++j)
          acc[i][j] = fmaf(a[i], bv[j], acc[i][j]);
    }
    __syncthreads();
  }

  // epilogue: relu + dot with W2 segment, reduce to per-row partials
  float p[8] = {0,0,0,0,0,0,0,0};
  #pragma unroll
  for (int j = 0; j < 8; ++j) {
    int col = (j < 4) ? (tx*4 + j) : (64 + tx*4 + (j - 4));
    int gn = n0 + col;
    float bb = b1[gn];
    float w  = W2[gn];
    #pragma unroll
    for (int i = 0; i < 8; ++i) {
      float v = acc[i][j] + bb;
      v = v > 0.f ? v : 0.f;
      p[i] = fmaf(v, w, p[i]);
    }
  }
  if (tid < BM) red[tid] = 0.f;
  __syncthreads();
  #pragma unroll
  for (int i = 0; i < 8; ++i) {
    int r = (i < 4) ? (ty*4 + i) : (64 + ty*4 + (i - 4));
    atomicAdd(&red[r], p[i]);
  }
  __syncthreads();
  if (tid < BM) atomicAdd(&logits[m0 + tid], red[tid]);
}

// ---------------- boundary decision + inclusive scan + segment extents ----------------
__global__ __launch_bounds__(256) void boundary_scan(
    const float* __restrict__ logits, const float* __restrict__ noise,
    int* __restrict__ segup, int* __restrict__ starts, int* __restrict__ ends,
    int* __restrict__ nsegs, int* __restrict__ kb)
{
  const int b = blockIdx.x;
  const int t = threadIdx.x;
  __shared__ unsigned char sh_hard[Lq];
  __shared__ int wsum[4];
  const int l0 = t * 8;
  int h[8];
  int localsum = 0;
  #pragma unroll
  for (int j = 0; j < 8; ++j) {
    int l = l0 + j;
    float u = noise[b * Lq + l];
    u = fminf(fmaxf(u, 1e-6f), 0.999999f);
    float z = (logits[b * Lq + l] + logf(u)) - log1pf(-u);
    int hd = (z > 0.f) ? 1 : 0;       // sigmoid(z) > 0.5  <=>  z > 0
    h[j] = hd;
    sh_hard[l] = (unsigned char)hd;
    localsum += hd;
  }
  // wave-inclusive scan of per-thread sums (wave64), then cross-wave via LDS
  int lane = t & 63, w = t >> 6;
  int v = localsum;
  #pragma unroll
  for (int off = 1; off < 64; off <<= 1) {
    int n = __shfl_up(v, off);
    if (lane >= off) v += n;
  }
  if (lane == 63) wsum[w] = v;
  __syncthreads();
  int wpre = 0;
  for (int i = 0; i < w; ++i) wpre += wsum[i];
  int run = wpre + (v - localsum);    // exclusive prefix for this thread
  #pragma unroll
  for (int j = 0; j < 8; ++j) {
    int l = l0 + j;
    run += h[j];                      // inclusive cumsum at l
    segup[b * Lq + l] = run;          // upsample segment id (0..2048)
    int sd = run - h[j];              // exclusive cumsum = downsample segment id
    int hp = (l == 0) ? 1 : (int)sh_hard[l - 1];
    if (hp) starts[b * Sq + sd] = l;              // first token of segment sd
    if (h[j] || l == Lq - 1) ends[b * Sq + sd] = l + 1;  // one past last token
    if (l == Lq - 1) { nsegs[b] = sd + 1; kb[b] = run; }
  }
}

// ---------------- segmented mean-pool -> shortened ----------------
__global__ __launch_bounds__(256) void pool_kernel(
    const float* __restrict__ x, const float* __restrict__ null_group,
    const int* __restrict__ starts, const int* __restrict__ ends,
    const int* __restrict__ nsegs, float* __restrict__ outS)
{
  const int so = blockIdx.x;     // 0..2048 (0 = null group)
  const int b  = blockIdx.y;
  const int d4 = threadIdx.x;    // 256 threads x float4 = 1024 floats
  float4* dst = (float4*)(outS + ((size_t)b * SP1 + so) * Dq) + d4;
  if (so == 0) { *dst = ((const float4*)null_group)[d4]; return; }
  int s = so - 1;
  if (s >= nsegs[b]) { float4 z; z.x = z.y = z.z = z.w = 0.f; *dst = z; return; }
  int st = starts[b * Sq + s], en = ends[b * Sq + s];
  float4 acc; acc.x = acc.y = acc.z = acc.w = 0.f;
  for (int l = st; l < en; ++l) {
    float4 vv = ((const float4*)(x + ((size_t)b * Lq + l) * Dq))[d4];
    acc.x += vv.x; acc.y += vv.y; acc.z += vv.z; acc.w += vv.w;
  }
  float inv = 1.f / (float)(en - st);
  acc.x *= inv; acc.y *= inv; acc.z *= inv; acc.w *= inv;
  *dst = acc;
}

// ---------------- upsample: gather shortened rows ----------------
__global__ __launch_bounds__(256) void upsample_kernel(
    const float* __restrict__ outS, const int* __restrict__ segup,
    float* __restrict__ outU)
{
  const int l = blockIdx.x, b = blockIdx.y;
  const int d4 = threadIdx.x;
  int sg = segup[b * Lq + l];
  ((float4*)(outU + ((size_t)b * Lq + l) * Dq))[d4] =
      ((const float4*)(outS + ((size_t)b * SP1 + sg) * Dq))[d4];
}

// ---------------- binomial consistency loss ----------------
__global__ void loss_kernel(const int* __restrict__ kb, float* __restrict__ out)
{
  int t = threadIdx.x;
  float lp = 0.f;
  if (t < Bq) {
    float k  = (float)kb[t];
    float Lf = (float)Lq;
    lp = lgammaf(Lf + 1.f) - lgammaf(k + 1.f) - lgammaf(Lf - k + 1.f)
       + k * logf(0.25f) + (Lf - k) * log1pf(-0.25f);
  }
  #pragma unroll
  for (int off = 32; off > 0; off >>= 1) lp += __shfl_down(lp, off);
  if (t == 0) out[0] = -(lp / (float)Bq) / (float)Lq;
}

extern "C" void kernel_launch(void* const* d_in, const int* in_sizes, int n_in,
                              void* d_out, int out_size, void* d_ws, size_t ws_size,
                              hipStream_t stream) {
  const float* x     = (const float*)d_in[0];
  const float* noise = (const float*)d_in[1];
  const float* W1    = (const float*)d_in[2];
  const float* b1    = (const float*)d_in[3];
  const float* W2    = (const float*)d_in[4];
  const float* b2    = (const float*)d_in[5];
  const float* ng    = (const float*)d_in[6];

  float* outS = (float*)d_out;                       // [8, 2049, 1024]
  float* outU = outS + (size_t)Bq * SP1 * Dq;        // [8, 2048, 1024]
  float* outL = outU + (size_t)Bq * Lq * Dq;         // scalar

  char* ws = (char*)d_ws;
  float* logits = (float*)(ws);                      // 16384 f32
  int*   segup  = (int*)(ws + 65536);                // 16384 i32
  int*   starts = (int*)(ws + 131072);               // 8*2048 i32
  int*   ends   = (int*)(ws + 196608);               // 8*2048 i32
  int*   nsegs  = (int*)(ws + 262144);               // 8 i32
  int*   kb     = (int*)(ws + 262144 + 256);         // 8 i32

  init_logits<<<Mq / 256, 256, 0, stream>>>(logits, b2);
  gemm_relu_gemv<<<dim3(Mq / BM, Dq / BN), 256, 0, stream>>>(x, W1, b1, W2, logits);
  boundary_scan<<<Bq, 256, 0, stream>>>(logits, noise, segup, starts, ends, nsegs, kb);
  pool_kernel<<<dim3(SP1, Bq), 256, 0, stream>>>(x, ng, starts, ends, nsegs, outS);
  upsample_kernel<<<dim3(Lq, Bq), 256, 0, stream>>>(outS, segup, outU);
  loss_kernel<<<1, 64, 0, stream>>>(kb, outL);
}